// Round 10
// baseline (1433.995 us; speedup 1.0000x reference)
//
#include <hip/hip_runtime.h>
#include <cstdint>

#define NN 300000
#define NE 600000
#define HD 128
#define NL 5
#define NG 8192
#define AVOC 128
#define BVOC 8
#define NAF 9
#define NBF 3
#define BN_EPS 1e-5f

#define SCAN_B 2048
#define SCAN_NB ((NN + SCAN_B - 1) / SCAN_B)   // 147

#define G1ROWS 128
#define G1BLK ((NN + G1ROWS - 1) / G1ROWS)     // 2344
#define GBM 256
#define GBLK ((NN + GBM - 1) / GBM)            // 1172

typedef unsigned short u16;
typedef unsigned int u32;
typedef __attribute__((ext_vector_type(8))) short bf16x8;
typedef __attribute__((ext_vector_type(4))) float f32x4;

static __device__ __forceinline__ void atomAddF(float* p, float v) { unsafeAtomicAdd(p, v); }

static __device__ __forceinline__ float bf2f(u16 v) {
  union { u32 u; float f; } c; c.u = ((u32)v) << 16; return c.f;
}
static __device__ __forceinline__ u16 f2bf(float f) {
  union { float f; u32 u; } c; c.f = f;
  u32 u = c.u;
  return (u16)((u + 0x7FFFu + ((u >> 16) & 1u)) >> 16);  // RNE
}
static __device__ __forceinline__ u32 cvtpk(float a, float b) {
  u32 r;
  asm("v_cvt_pk_bf16_f32 %0, %1, %2" : "=v"(r) : "v"(a), "v"(b));
  return r;  // lo16 = bf16(a), hi16 = bf16(b), RNE
}
static __device__ __forceinline__ void unp8(uint4 p, float* v) {
  v[0] = bf2f((u16)(p.x & 0xffff)); v[1] = bf2f((u16)(p.x >> 16));
  v[2] = bf2f((u16)(p.y & 0xffff)); v[3] = bf2f((u16)(p.y >> 16));
  v[4] = bf2f((u16)(p.z & 0xffff)); v[5] = bf2f((u16)(p.z >> 16));
  v[6] = bf2f((u16)(p.w & 0xffff)); v[7] = bf2f((u16)(p.w >> 16));
}
static __device__ __forceinline__ uint4 pk8(const float* v) {
  uint4 p;
  p.x = ((u32)f2bf(v[1]) << 16) | f2bf(v[0]);
  p.y = ((u32)f2bf(v[3]) << 16) | f2bf(v[2]);
  p.z = ((u32)f2bf(v[5]) << 16) | f2bf(v[4]);
  p.w = ((u32)f2bf(v[7]) << 16) | f2bf(v[6]);
  return p;
}

// split fp32[8] -> hi bf16x8 + lo bf16x8  (hi+lo represents v to ~2^-17 rel)
static __device__ __forceinline__ void split8(const float* v, bf16x8& hi, bf16x8& lo) {
  union { u32 u[4]; bf16x8 h; } H, L;
  H.u[0] = cvtpk(v[0], v[1]); H.u[1] = cvtpk(v[2], v[3]);
  H.u[2] = cvtpk(v[4], v[5]); H.u[3] = cvtpk(v[6], v[7]);
  float r[8];
  r[0] = bf2f((u16)(H.u[0] & 0xffff)); r[1] = bf2f((u16)(H.u[0] >> 16));
  r[2] = bf2f((u16)(H.u[1] & 0xffff)); r[3] = bf2f((u16)(H.u[1] >> 16));
  r[4] = bf2f((u16)(H.u[2] & 0xffff)); r[5] = bf2f((u16)(H.u[2] >> 16));
  r[6] = bf2f((u16)(H.u[3] & 0xffff)); r[7] = bf2f((u16)(H.u[3] >> 16));
  L.u[0] = cvtpk(v[0] - r[0], v[1] - r[1]); L.u[1] = cvtpk(v[2] - r[2], v[3] - r[3]);
  L.u[2] = cvtpk(v[4] - r[4], v[5] - r[5]); L.u[3] = cvtpk(v[6] - r[6], v[7] - r[7]);
  hi = H.h; lo = L.h;
}

// ================= CSR construction =================
__global__ __launch_bounds__(256) void count_k(const int* __restrict__ ei,
    int* __restrict__ cnt_row, int* __restrict__ cnt_col) {
  int e = blockIdx.x * 256 + threadIdx.x;
  if (e >= NE) return;
  atomicAdd(&cnt_row[ei[e]], 1);
  atomicAdd(&cnt_col[ei[NE + e]], 1);
}

__global__ __launch_bounds__(256) void scan_block_k(int* __restrict__ P, int* __restrict__ bsum) {
  __shared__ int s[256];
  int b = blockIdx.x, t = threadIdx.x;
  int base = b * SCAN_B + t * 8;
  int v[8]; int ts = 0;
#pragma unroll
  for (int j = 0; j < 8; j++) { v[j] = (base + j < NN) ? P[base + j] : 0; ts += v[j]; }
  s[t] = ts;
  __syncthreads();
  for (int off = 1; off < 256; off <<= 1) {
    int tmp = 0;
    if (t >= off) tmp = s[t - off];
    __syncthreads();
    if (t >= off) s[t] += tmp;
    __syncthreads();
  }
  if (t == 255) bsum[b] = s[255];
  int run = (t == 0) ? 0 : s[t - 1];
#pragma unroll
  for (int j = 0; j < 8; j++) {
    if (base + j < NN) P[base + j] = run;
    run += v[j];
  }
}

__global__ __launch_bounds__(256) void scan_tops_k(int* __restrict__ bsum, int* __restrict__ totOut) {
  __shared__ int s[256];
  int t = threadIdx.x;
  s[t] = (t < SCAN_NB) ? bsum[t] : 0;
  __syncthreads();
  for (int off = 1; off < 256; off <<= 1) {
    int tmp = 0;
    if (t >= off) tmp = s[t - off];
    __syncthreads();
    if (t >= off) s[t] += tmp;
    __syncthreads();
  }
  if (t < SCAN_NB) bsum[t] = (t == 0) ? 0 : s[t - 1];
  if (t == 255) *totOut = s[255];
}

__global__ __launch_bounds__(256) void scan_add_k(int* __restrict__ P, const int* __restrict__ bsum) {
  int b = blockIdx.x, t = threadIdx.x;
  int off = bsum[b];
  int base = b * SCAN_B + t * 8;
#pragma unroll
  for (int j = 0; j < 8; j++)
    if (base + j < NN) P[base + j] += off;
}

// fill: adjc = combined bond-attr index (u16) in CSR-row order; adj_col = src node ids
__global__ __launch_bounds__(256) void fill_k(const int* __restrict__ ei,
    const int* __restrict__ ea,
    const int* __restrict__ ptr_row, const int* __restrict__ ptr_col,
    int* __restrict__ fillr, int* __restrict__ fillc,
    u16* __restrict__ adjc, int* __restrict__ adj_col) {
  int e = blockIdx.x * 256 + threadIdx.x;
  if (e >= NE) return;
  int r = ei[e], c = ei[NE + e];
  int a0 = ea[e * 3 + 0], a1 = ea[e * 3 + 1], a2 = ea[e * 3 + 2];
  int p1 = atomicAdd(&fillr[r], 1);
  adjc[ptr_row[r] + p1] = (u16)(a0 + (a1 << 3) + (a2 << 6));
  int p2 = atomicAdd(&fillc[c], 1);
  adj_col[ptr_col[c] + p2] = r;
}

__global__ __launch_bounds__(256) void inv_k(const int* __restrict__ ptr_row, float* __restrict__ inv) {
  int n = blockIdx.x * 256 + threadIdx.x;
  if (n < NN) inv[n] = 1.0f / ((float)(ptr_row[n + 1] - ptr_row[n]) + 1.0f);
}

__global__ __launch_bounds__(256) void gp_k(const int* __restrict__ batch, int* __restrict__ gp) {
  int g = blockIdx.x * 256 + threadIdx.x;
  if (g > NG) return;
  int lo = 0, hi = NN;
  while (lo < hi) { int mid = (lo + hi) >> 1; if (batch[mid] < g) lo = mid + 1; else hi = mid; }
  gp[g] = lo;
}

// W split/transpose: Wt[m][c][k] = bf16_hi/lo of W_m[k][c];  m<5 -> w1[m], else w2[m-5]
__global__ __launch_bounds__(256) void wsplit_k(const float* __restrict__ w1,
    const float* __restrict__ w2, u16* __restrict__ Wt_hi, u16* __restrict__ Wt_lo) {
  int m = blockIdx.x;
  const float* W = (m < NL) ? (w1 + (size_t)m * HD * HD) : (w2 + (size_t)(m - NL) * HD * HD);
  int t = threadIdx.x;
  for (int p = 0; p < 64; p++) {
    int o = p * 256 + t;            // linear over [c][k]
    int c = o >> 7, k = o & 127;
    float w = W[k * HD + c];
    u16 hi = f2bf(w);
    float lo = w - bf2f(hi);
    Wt_hi[(size_t)m * HD * HD + o] = hi;
    Wt_lo[(size_t)m * HD * HD + o] = f2bf(lo);
  }
}

// combined bond table: cmb[l][c][ch] = emb0[c&7] + emb1[(c>>3)&7] + emb2[c>>6]  (fp32, same add order)
__global__ __launch_bounds__(128) void cmb_k(const float* __restrict__ bond_emb,
    float* __restrict__ cmb) {
  int b = blockIdx.x;                 // l*512 + c
  int l = b >> 9, c = b & 511;
  int t = threadIdx.x;
  const float* be = bond_emb + (size_t)l * NBF * BVOC * HD;
  float v = be[(c & 7) * HD + t] + be[(BVOC + ((c >> 3) & 7)) * HD + t]
          + be[(2 * BVOC + (c >> 6)) * HD + t];
  cmb[(size_t)b * HD + t] = v;
}

// ================= model kernels =================

// layer 0: atom encoder + bond gather -> A (bf16)
__global__ __launch_bounds__(256) void bond_enc_k(
    const float* __restrict__ cmb, const int* __restrict__ ptr_row,
    const u16* __restrict__ adjc, const float* __restrict__ inv,
    const int* __restrict__ x, const float* __restrict__ emb,
    u16* __restrict__ A) {
  __shared__ int sx[16 * NAF];
  int t = threadIdx.x;
  int nb = blockIdx.x * 16;
  int n = nb + (t >> 4);
  int c8 = t & 15;
  if (t < 16 * NAF && nb * NAF + t < NN * NAF) sx[t] = x[nb * NAF + t];
  __syncthreads();
  if (n >= NN) return;
  int beg = ptr_row[n], end = ptr_row[n + 1];
  float acc[8] = {0.f, 0.f, 0.f, 0.f, 0.f, 0.f, 0.f, 0.f};
  {
    int i = beg;
    int ca = (beg < end) ? (int)adjc[beg] : 0;
    int cb = (beg + 1 < end) ? (int)adjc[beg + 1] : 0;
    while (i + 1 < end) {
      const float* pa = cmb + ((size_t)ca << 7) + c8 * 8;
      const float* pb = cmb + ((size_t)cb << 7) + c8 * 8;
      float4 a0 = *(const float4*)pa, a1 = *(const float4*)(pa + 4);
      float4 b0 = *(const float4*)pb, b1 = *(const float4*)(pb + 4);
      i += 2;
      if (i < end)     ca = (int)adjc[i];
      if (i + 1 < end) cb = (int)adjc[i + 1];
      acc[0] += a0.x; acc[1] += a0.y; acc[2] += a0.z; acc[3] += a0.w;
      acc[4] += a1.x; acc[5] += a1.y; acc[6] += a1.z; acc[7] += a1.w;
      acc[0] += b0.x; acc[1] += b0.y; acc[2] += b0.z; acc[3] += b0.w;
      acc[4] += b1.x; acc[5] += b1.y; acc[6] += b1.z; acc[7] += b1.w;
    }
    if (i < end) {
      const float* pa = cmb + ((size_t)ca << 7) + c8 * 8;
      float4 a0 = *(const float4*)pa, a1 = *(const float4*)(pa + 4);
      acc[0] += a0.x; acc[1] += a0.y; acc[2] += a0.z; acc[3] += a0.w;
      acc[4] += a1.x; acc[5] += a1.y; acc[6] += a1.z; acc[7] += a1.w;
    }
  }
  float h[8];
#pragma unroll
  for (int j = 0; j < 8; j++) h[j] = 0.f;
#pragma unroll
  for (int f = 0; f < NAF; f++) {
    int v = sx[(t >> 4) * NAF + f];
    const float* e = emb + ((size_t)(f * AVOC + v)) * HD + c8 * 8;
    float4 e0 = *(const float4*)e;
    float4 e1 = *(const float4*)(e + 4);
    h[0] += e0.x; h[1] += e0.y; h[2] += e0.z; h[3] += e0.w;
    h[4] += e1.x; h[5] += e1.y; h[6] += e1.z; h[7] += e1.w;
  }
  float iv = inv[n];
#pragma unroll
  for (int j = 0; j < 8; j++) h[j] = fmaf(acc[j], iv, h[j]);
  *(uint4*)(A + (size_t)n * HD + c8 * 8) = pk8(h);
}

// layers 1..4: pure streaming: A = relu(BN(Z2)) + inv * BAGG  (BAGG precomputed by gemm2)
__global__ __launch_bounds__(256) void bond_stream_k(
    const u16* __restrict__ Z2, const u16* __restrict__ BAGG,
    const float* __restrict__ inv, const float* __restrict__ stR,
    const float* __restrict__ bg, const float* __restrict__ bb_,
    u16* __restrict__ A) {
  __shared__ float sss[256];
  int t = threadIdx.x;
  if (t < 128) {
    float mean = stR[t] * (1.0f / NN);
    float var = stR[128 + t] * (1.0f / NN) - mean * mean;
    float sc = bg[t] * rsqrtf(var + BN_EPS);
    sss[t] = sc;
    sss[128 + t] = fmaf(-mean, sc, bb_[t]);
  }
  __syncthreads();
  int gid = blockIdx.x * 256 + t;
  if (gid >= NN * 16) return;
  int n = gid >> 4, c8 = gid & 15;
  uint4 pz = *(const uint4*)(Z2 + (size_t)n * HD + c8 * 8);
  uint4 pb = *(const uint4*)(BAGG + (size_t)n * HD + c8 * 8);
  float h[8], g[8];
  unp8(pz, h); unp8(pb, g);
  float iv = inv[n];
#pragma unroll
  for (int j = 0; j < 8; j++) {
    h[j] = fmaxf(fmaf(h[j], sss[c8 * 8 + j], sss[128 + c8 * 8 + j]), 0.f);
    h[j] = fmaf(g[j], iv, h[j]);
  }
  *(uint4*)(A + (size_t)n * HD + c8 * 8) = pk8(h);
}

// ---------------- GEMM1 with fused GIN aggregation (gather hoisted, unroll-2) ----------------
__global__ __launch_bounds__(512, 4) void gemm1_aggr_k(
    const u16* __restrict__ A, const int* __restrict__ ptr_col,
    const int* __restrict__ adj_col, const float* __restrict__ eps, int lyr,
    const u16* __restrict__ Whi, const u16* __restrict__ Wlo,
    const float* __restrict__ bias, u16* __restrict__ Z1,
    float* __restrict__ stats) {
  __shared__ u16 sW[2 * HD * HD];     // 64 KB: hi then lo, [col][k], XOR-swizzled
  const int tid = threadIdx.x;
#pragma unroll
  for (int p = 0; p < 4; p++) {
    int idx = tid + p * 512;
    int col = idx >> 4, k16 = idx & 15;
    uint4 vh = *(const uint4*)(Whi + idx * 8);
    uint4 vl = *(const uint4*)(Wlo + idx * 8);
    int so = (col << 7) + ((k16 << 3) ^ ((col & 7) << 3));
    *(uint4*)(sW + so) = vh;
    *(uint4*)(sW + HD * HD + so) = vl;
  }
  __syncthreads();

  const float se = 1.0f + eps[lyr];
  const int l = tid & 63, w = tid >> 6;
  const int lr = l & 15, lk = l >> 4;
  const int rw = blockIdx.x * G1ROWS + w * 16;  // wave's 16 rows
  const int gr = rw + lr;                       // this lane's row
  const int kb0 = lk * 8;                       // lane's col base within each 32-chunk

  float z[4][8];
#pragma unroll
  for (int ks = 0; ks < 4; ks++)
#pragma unroll
    for (int j = 0; j < 8; j++) z[ks][j] = 0.f;

  if (gr < NN) {
    const u16* ap = A + (size_t)gr * HD + kb0;
    uint4 s0 = *(const uint4*)(ap);
    uint4 s1 = *(const uint4*)(ap + 32);
    uint4 s2 = *(const uint4*)(ap + 64);
    uint4 s3 = *(const uint4*)(ap + 96);
    int beg = ptr_col[gr], end = ptr_col[gr + 1];
    {
      float v[8];
      unp8(s0, v);
#pragma unroll
      for (int j = 0; j < 8; j++) z[0][j] = v[j] * se;
      unp8(s1, v);
#pragma unroll
      for (int j = 0; j < 8; j++) z[1][j] = v[j] * se;
      unp8(s2, v);
#pragma unroll
      for (int j = 0; j < 8; j++) z[2][j] = v[j] * se;
      unp8(s3, v);
#pragma unroll
      for (int j = 0; j < 8; j++) z[3][j] = v[j] * se;
    }
    int i = beg;
    int srcA = (beg < end) ? adj_col[beg] : 0;
    int srcB = (beg + 1 < end) ? adj_col[beg + 1] : 0;
    while (i + 1 < end) {
      const u16* pa = A + (size_t)srcA * HD + kb0;
      const u16* pb = A + (size_t)srcB * HD + kb0;
      uint4 a0 = *(const uint4*)(pa);
      uint4 a1 = *(const uint4*)(pa + 32);
      uint4 a2 = *(const uint4*)(pa + 64);
      uint4 a3 = *(const uint4*)(pa + 96);
      uint4 b0 = *(const uint4*)(pb);
      uint4 b1 = *(const uint4*)(pb + 32);
      uint4 b2 = *(const uint4*)(pb + 64);
      uint4 b3 = *(const uint4*)(pb + 96);
      i += 2;
      if (i < end)     srcA = adj_col[i];
      if (i + 1 < end) srcB = adj_col[i + 1];
      float u[8];
      unp8(a0, u);
#pragma unroll
      for (int j = 0; j < 8; j++) z[0][j] += u[j];
      unp8(a1, u);
#pragma unroll
      for (int j = 0; j < 8; j++) z[1][j] += u[j];
      unp8(a2, u);
#pragma unroll
      for (int j = 0; j < 8; j++) z[2][j] += u[j];
      unp8(a3, u);
#pragma unroll
      for (int j = 0; j < 8; j++) z[3][j] += u[j];
      unp8(b0, u);
#pragma unroll
      for (int j = 0; j < 8; j++) z[0][j] += u[j];
      unp8(b1, u);
#pragma unroll
      for (int j = 0; j < 8; j++) z[1][j] += u[j];
      unp8(b2, u);
#pragma unroll
      for (int j = 0; j < 8; j++) z[2][j] += u[j];
      unp8(b3, u);
#pragma unroll
      for (int j = 0; j < 8; j++) z[3][j] += u[j];
    }
    if (i < end) {
      const u16* pa = A + (size_t)srcA * HD + kb0;
      uint4 a0 = *(const uint4*)(pa);
      uint4 a1 = *(const uint4*)(pa + 32);
      uint4 a2 = *(const uint4*)(pa + 64);
      uint4 a3 = *(const uint4*)(pa + 96);
      float u[8];
      unp8(a0, u);
#pragma unroll
      for (int j = 0; j < 8; j++) z[0][j] += u[j];
      unp8(a1, u);
#pragma unroll
      for (int j = 0; j < 8; j++) z[1][j] += u[j];
      unp8(a2, u);
#pragma unroll
      for (int j = 0; j < 8; j++) z[2][j] += u[j];
      unp8(a3, u);
#pragma unroll
      for (int j = 0; j < 8; j++) z[3][j] += u[j];
    }
  }

  bf16x8 ah[4], al[4];
#pragma unroll
  for (int ks = 0; ks < 4; ks++) split8(z[ks], ah[ks], al[ks]);

  f32x4 acc[8];
#pragma unroll
  for (int jt = 0; jt < 8; jt++) acc[jt] = (f32x4){0.f, 0.f, 0.f, 0.f};
#pragma unroll
  for (int ks = 0; ks < 4; ks++) {
    const int kb = ks * 32 + kb0;
#pragma unroll
    for (int jt = 0; jt < 8; jt++) {
      int col = jt * 16 + lr;
      int so = (col << 7) + (kb ^ ((col & 7) << 3));
      bf16x8 bh = *(const bf16x8*)(sW + so);
      bf16x8 bl = *(const bf16x8*)(sW + HD * HD + so);
      acc[jt] = __builtin_amdgcn_mfma_f32_16x16x32_bf16(ah[ks], bh, acc[jt], 0, 0, 0);
      acc[jt] = __builtin_amdgcn_mfma_f32_16x16x32_bf16(al[ks], bh, acc[jt], 0, 0, 0);
      acc[jt] = __builtin_amdgcn_mfma_f32_16x16x32_bf16(ah[ks], bl, acc[jt], 0, 0, 0);
    }
  }

  // epilogue: +bias, BN stats (fp32 pre-rounding), packed bf16 stores
  float bb[8];
#pragma unroll
  for (int jt = 0; jt < 8; jt++) bb[jt] = bias[jt * 16 + lr];
  float cs[8], cq[8];
#pragma unroll
  for (int jt = 0; jt < 8; jt++) { cs[jt] = 0.f; cq[jt] = 0.f; }
#pragma unroll
  for (int j = 0; j < 4; j++) {
    int gr2 = rw + lk * 4 + j;
    bool ok = gr2 < NN;
#pragma unroll
    for (int jt = 0; jt < 8; jt++) {
      float o = acc[jt][j] + bb[jt];
      if (ok) { cs[jt] += o; cq[jt] += o * o; }
      float on = __shfl_xor(o, 1);
      u32 pw = cvtpk(o, on);
      if (ok && !(l & 1))
        *(u32*)(Z1 + (size_t)gr2 * HD + jt * 16 + lr) = pw;
    }
  }
#pragma unroll
  for (int jt = 0; jt < 8; jt++) {
    cs[jt] += __shfl_xor(cs[jt], 16); cs[jt] += __shfl_xor(cs[jt], 32);
    cq[jt] += __shfl_xor(cq[jt], 16); cq[jt] += __shfl_xor(cq[jt], 32);
  }
  __syncthreads();
  float* sS = (float*)sW;
  if (lk == 0) {
#pragma unroll
    for (int jt = 0; jt < 8; jt++) {
      sS[w * HD + jt * 16 + lr] = cs[jt];
      sS[1024 + w * HD + jt * 16 + lr] = cq[jt];
    }
  }
  __syncthreads();
  if (tid < HD) {
    float s = 0.f, q = 0.f;
#pragma unroll
    for (int g = 0; g < 8; g++) { s += sS[g * HD + tid]; q += sS[1024 + g * HD + tid]; }
    atomAddF(&stats[tid], s);
    atomAddF(&stats[HD + tid], q);
  }
}

// ---------------- GEMM2: relu(BN1(Z1)) @ W2 + b2 -> Z2 bf16 + BN stats ----------------
// BN1 affine computed in-kernel from gemm1's raw sums.  After the MFMA work each
// wave also gathers next layer's bond aggregation for ITS OWN 32 rows and writes
// it (bf16) into baggOut — which aliases Z1 (rows are wave-local: safe).
__global__ __launch_bounds__(512, 4) void gemm2_k(
    const u16* __restrict__ Z1, const float* __restrict__ stR,
    const float* __restrict__ g1, const float* __restrict__ b1_,
    const u16* __restrict__ Whi, const u16* __restrict__ Wlo,
    const float* __restrict__ bias, u16* __restrict__ Z2,
    float* __restrict__ stats,
    const int* __restrict__ ptr_row, const u16* __restrict__ adjc,
    const float* __restrict__ cmbN, u16* __restrict__ baggOut) {
  __shared__ u16 sW[2 * HD * HD];
  __shared__ float sss[256];
  const int tid = threadIdx.x;
#pragma unroll
  for (int p = 0; p < 4; p++) {
    int idx = tid + p * 512;
    int col = idx >> 4, k16 = idx & 15;
    uint4 vh = *(const uint4*)(Whi + idx * 8);
    uint4 vl = *(const uint4*)(Wlo + idx * 8);
    int so = (col << 7) + ((k16 << 3) ^ ((col & 7) << 3));
    *(uint4*)(sW + so) = vh;
    *(uint4*)(sW + HD * HD + so) = vl;
  }
  if (tid < 128) {
    float mean = stR[tid] * (1.0f / NN);
    float var = stR[128 + tid] * (1.0f / NN) - mean * mean;
    float sc = g1[tid] * rsqrtf(var + BN_EPS);
    sss[tid] = sc;
    sss[128 + tid] = fmaf(-mean, sc, b1_[tid]);
  }
  __syncthreads();

  const int l = tid & 63, w = tid >> 6;
  const int lr = l & 15, lk = l >> 4;
  const int rw = blockIdx.x * GBM + w * 32;
  f32x4 acc[2][8];
#pragma unroll
  for (int i = 0; i < 2; i++)
#pragma unroll
    for (int j = 0; j < 8; j++) acc[i][j] = (f32x4){0.f, 0.f, 0.f, 0.f};

#pragma unroll
  for (int ks = 0; ks < 4; ks++) {
    const int kb = ks * 32 + lk * 8;
    bf16x8 ah[2], al[2];
#pragma unroll
    for (int i = 0; i < 2; i++) {
      int gr = rw + i * 16 + lr;
      uint4 p = make_uint4(0u, 0u, 0u, 0u);
      if (gr < NN) p = *(const uint4*)(Z1 + (size_t)gr * HD + kb);
      float v[8]; unp8(p, v);
#pragma unroll
      for (int j = 0; j < 8; j++)
        v[j] = fmaxf(fmaf(v[j], sss[kb + j], sss[128 + kb + j]), 0.f);
      split8(v, ah[i], al[i]);
    }
#pragma unroll
    for (int jt = 0; jt < 8; jt++) {
      int col = jt * 16 + lr;
      int so = (col << 7) + (kb ^ ((col & 7) << 3));
      bf16x8 bh = *(const bf16x8*)(sW + so);
      bf16x8 bl = *(const bf16x8*)(sW + HD * HD + so);
#pragma unroll
      for (int i = 0; i < 2; i++) {
        acc[i][jt] = __builtin_amdgcn_mfma_f32_16x16x32_bf16(ah[i], bh, acc[i][jt], 0, 0, 0);
        acc[i][jt] = __builtin_amdgcn_mfma_f32_16x16x32_bf16(al[i], bh, acc[i][jt], 0, 0, 0);
        acc[i][jt] = __builtin_amdgcn_mfma_f32_16x16x32_bf16(ah[i], bl, acc[i][jt], 0, 0, 0);
      }
    }
  }

  float bb[8];
#pragma unroll
  for (int jt = 0; jt < 8; jt++) bb[jt] = bias[jt * 16 + lr];
  float cs[8], cq[8];
#pragma unroll
  for (int jt = 0; jt < 8; jt++) { cs[jt] = 0.f; cq[jt] = 0.f; }
#pragma unroll
  for (int i = 0; i < 2; i++)
#pragma unroll
    for (int j = 0; j < 4; j++) {
      int gr = rw + i * 16 + lk * 4 + j;
      bool ok = gr < NN;
#pragma unroll
      for (int jt = 0; jt < 8; jt++) {
        float o = acc[i][jt][j] + bb[jt];
        if (ok) { cs[jt] += o; cq[jt] += o * o; }
        float on = __shfl_xor(o, 1);
        u32 pw = cvtpk(o, on);
        if (ok && !(l & 1))
          *(u32*)(Z2 + (size_t)gr * HD + jt * 16 + lr) = pw;
      }
    }
#pragma unroll
  for (int jt = 0; jt < 8; jt++) {
    cs[jt] += __shfl_xor(cs[jt], 16); cs[jt] += __shfl_xor(cs[jt], 32);
    cq[jt] += __shfl_xor(cq[jt], 16); cq[jt] += __shfl_xor(cq[jt], 32);
  }
  __syncthreads();
  float* sS = (float*)sW;
  if (lk == 0) {
#pragma unroll
    for (int jt = 0; jt < 8; jt++) {
      sS[w * HD + jt * 16 + lr] = cs[jt];
      sS[1024 + w * HD + jt * 16 + lr] = cq[jt];
    }
  }
  __syncthreads();
  if (tid < HD) {
    float s = 0.f, q = 0.f;
#pragma unroll
    for (int g = 0; g < 8; g++) { s += sS[g * HD + tid]; q += sS[1024 + g * HD + tid]; }
    atomAddF(&stats[tid], s);
    atomAddF(&stats[HD + tid], q);
  }

  // ---- next-layer bond aggregation for this wave's own 32 rows (overlaps
  // with other blocks' MFMA work).  All of this wave's Z1 reads completed
  // before these stores (program order + waitcnt on data use) -> safe alias.
  if (baggOut != nullptr) {
    const int nd4 = l >> 4;       // 0..3: node within quad
    const int c8g = l & 15;       // channel group
#pragma unroll
    for (int ps = 0; ps < 8; ps++) {
      int n = rw + ps * 4 + nd4;
      if (n < NN) {
        int bgn = ptr_row[n], endn = ptr_row[n + 1];
        float ac[8] = {0.f, 0.f, 0.f, 0.f, 0.f, 0.f, 0.f, 0.f};
        int i = bgn;
        int ca = (bgn < endn) ? (int)adjc[bgn] : 0;
        int cb = (bgn + 1 < endn) ? (int)adjc[bgn + 1] : 0;
        while (i + 1 < endn) {
          const float* pa = cmbN + ((size_t)ca << 7) + c8g * 8;
          const float* pb = cmbN + ((size_t)cb << 7) + c8g * 8;
          float4 a0 = *(const float4*)pa, a1 = *(const float4*)(pa + 4);
          float4 b0 = *(const float4*)pb, b1 = *(const float4*)(pb + 4);
          i += 2;
          if (i < endn)     ca = (int)adjc[i];
          if (i + 1 < endn) cb = (int)adjc[i + 1];
          ac[0] += a0.x; ac[1] += a0.y; ac[2] += a0.z; ac[3] += a0.w;
          ac[4] += a1.x; ac[5] += a1.y; ac[6] += a1.z; ac[7] += a1.w;
          ac[0] += b0.x; ac[1] += b0.y; ac[2] += b0.z; ac[3] += b0.w;
          ac[4] += b1.x; ac[5] += b1.y; ac[6] += b1.z; ac[7] += b1.w;
        }
        if (i < endn) {
          const float* pa = cmbN + ((size_t)ca << 7) + c8g * 8;
          float4 a0 = *(const float4*)pa, a1 = *(const float4*)(pa + 4);
          ac[0] += a0.x; ac[1] += a0.y; ac[2] += a0.z; ac[3] += a0.w;
          ac[4] += a1.x; ac[5] += a1.y; ac[6] += a1.z; ac[7] += a1.w;
        }
        *(uint4*)(baggOut + (size_t)n * HD + c8g * 8) = pk8(ac);
      }
    }
  }
}

// fused BN (layer 4, computed from raw sums, no relu) + global_add_pool + MLP head
__global__ __launch_bounds__(128) void pool_final_k(const u16* __restrict__ Z2,
    const float* __restrict__ stR,
    const float* __restrict__ bg, const float* __restrict__ bb_,
    const int* __restrict__ gp,
    const float* __restrict__ cw1, const float* __restrict__ cb1,
    const float* __restrict__ cw2, const float* __restrict__ cb2,
    float* __restrict__ out) {
  __shared__ float sp[128];
  __shared__ float sh[128];
  int g = blockIdx.x, t = threadIdx.x;
  float mean = stR[t] * (1.0f / NN);
  float var = stR[128 + t] * (1.0f / NN) - mean * mean;
  float sc = bg[t] * rsqrtf(var + BN_EPS);
  float shf = fmaf(-mean, sc, bb_[t]);
  int beg = gp[g], end = gp[g + 1];
  float acc = 0.f;
  for (int n = beg; n < end; n++) acc += bf2f(Z2[(size_t)n * HD + t]);
  sp[t] = fmaf(acc, sc, (float)(end - beg) * shf);
  __syncthreads();
  float h1 = cb1[t];
#pragma unroll
  for (int k = 0; k < HD; k++) h1 = fmaf(sp[k], cw1[k * HD + t], h1);
  h1 = fmaxf(h1, 0.f);
  sh[t] = h1 * cw2[t];
  __syncthreads();
  for (int s = 64; s >= 1; s >>= 1) {
    if (t < s) sh[t] += sh[t + s];
    __syncthreads();
  }
  if (t == 0) out[g] = sh[0] + cb2[0];
}

extern "C" void kernel_launch(void* const* d_in, const int* in_sizes, int n_in,
                              void* d_out, int out_size, void* d_ws, size_t ws_size,
                              hipStream_t stream) {
  const int*   x        = (const int*)d_in[0];
  const int*   ei       = (const int*)d_in[1];
  const int*   ea       = (const int*)d_in[2];
  const int*   batch    = (const int*)d_in[3];
  const float* atom_emb = (const float*)d_in[4];
  const float* bond_emb = (const float*)d_in[5];
  const float* eps      = (const float*)d_in[6];
  const float* w1       = (const float*)d_in[7];
  const float* b1       = (const float*)d_in[8];
  const float* bn1_g    = (const float*)d_in[9];
  const float* bn1_b    = (const float*)d_in[10];
  const float* w2       = (const float*)d_in[11];
  const float* b2       = (const float*)d_in[12];
  const float* bn_g     = (const float*)d_in[13];
  const float* bn_b     = (const float*)d_in[14];
  const float* cw1      = (const float*)d_in[15];
  const float* cb1      = (const float*)d_in[16];
  const float* cw2      = (const float*)d_in[17];
  const float* cb2      = (const float*)d_in[18];
  float* out = (float*)d_out;

  const size_t NH = (size_t)NN * HD;
  float* ws = (float*)d_ws;
  float* stats   = ws;                               // 5*1024 floats (raw sums)
  int*   ptr_row = (int*)(ws + 5 * 1024);            // NN+1
  int*   ptr_col = ptr_row + (NN + 1);               // NN+1
  u16*   adjc    = (u16*)(ptr_col + (NN + 1));       // NE u16 (slot sized NE ints)
  int*   adj_col = (int*)adjc + NE;                  // NE
  int*   gp      = adj_col + NE;                     // NG+1
  float* inv     = (float*)(gp + (NG + 1));          // NN
  size_t off = 5 * 1024 + 2 * (size_t)(NN + 1) + 2 * (size_t)NE + (NG + 1) + NN;
  off = (off + 3) & ~(size_t)3;                      // 16B align
  float* B = ws + off;                               // NH fp32 bytes: Z1 | Z2 (bf16 halves)
  u16*   Z1 = (u16*)B;                               // lower NH*2 bytes (gemm1 out / BAGG)
  u16*   Z2 = Z1 + NH;                               // upper NH*2 bytes
  u16*   A  = (u16*)(B + NH);                        // NH bf16 (h_in)
  u16*   Wt_hi = A + NH;                             // 10 * 128*128 bf16
  u16*   Wt_lo = Wt_hi + 10 * HD * HD;               // 10 * 128*128 bf16
  float* cmb   = (float*)(Wt_lo + 10 * HD * HD);     // 5 * 512 * 128 fp32
  // setup-only temps aliased into B (first written by gemm1_aggr in layer 0)
  int* fillr = (int*)B;
  int* fillc = fillr + NN;
  int* bsums = fillc + NN;                           // SCAN_NB ints

  const int nb_node = (NN + 15) / 16;                        // 18750
  const int nb_n16  = (int)(((size_t)NN * 16 + 255) / 256);  // 18750
  const int nb_n256 = (NN + 255) / 256;                      // 1172
  const int nb_e    = (NE + 255) / 256;                      // 2344

  // ---- setup: CSR build + weight split + bond table + graph offsets ----
  hipMemsetAsync(stats, 0, 5 * 1024 * sizeof(float), stream);
  hipMemsetAsync(ptr_row, 0, 2 * (NN + 1) * sizeof(int), stream);
  hipMemsetAsync(fillr, 0, 2 * NN * sizeof(int), stream);

  count_k<<<nb_e, 256, 0, stream>>>(ei, ptr_row, ptr_col);
  scan_block_k<<<SCAN_NB, 256, 0, stream>>>(ptr_row, bsums);
  scan_tops_k<<<1, 256, 0, stream>>>(bsums, &ptr_row[NN]);
  scan_add_k<<<SCAN_NB, 256, 0, stream>>>(ptr_row, bsums);
  scan_block_k<<<SCAN_NB, 256, 0, stream>>>(ptr_col, bsums);
  scan_tops_k<<<1, 256, 0, stream>>>(bsums, &ptr_col[NN]);
  scan_add_k<<<SCAN_NB, 256, 0, stream>>>(ptr_col, bsums);
  inv_k<<<nb_n256, 256, 0, stream>>>(ptr_row, inv);
  fill_k<<<nb_e, 256, 0, stream>>>(ei, ea, ptr_row, ptr_col, fillr, fillc, adjc, adj_col);
  wsplit_k<<<2 * NL, 256, 0, stream>>>(w1, w2, Wt_hi, Wt_lo);
  cmb_k<<<NL * 512, 128, 0, stream>>>(bond_emb, cmb);
  gp_k<<<(NG + 1 + 255) / 256, 256, 0, stream>>>(batch, gp);

  // ---- layers ----
  for (int l = 0; l < NL; l++) {
    float* st = stats + (size_t)l * 1024;
    if (l == 0) {
      bond_enc_k<<<nb_node, 256, 0, stream>>>(cmb, ptr_row, adjc, inv, x, atom_emb, A);
    } else {
      bond_stream_k<<<nb_n16, 256, 0, stream>>>(Z2, Z1 /*BAGG*/, inv,
          stats + (size_t)(l - 1) * 1024 + 512,
          bn_g + (size_t)(l - 1) * HD, bn_b + (size_t)(l - 1) * HD, A);
    }
    gemm1_aggr_k<<<G1BLK, 512, 0, stream>>>(A, ptr_col, adj_col, eps, l,
        Wt_hi + (size_t)l * HD * HD, Wt_lo + (size_t)l * HD * HD,
        b1 + (size_t)l * HD, Z1, st);
    gemm2_k<<<GBLK, 512, 0, stream>>>(Z1, st,
        bn1_g + (size_t)l * HD, bn1_b + (size_t)l * HD,
        Wt_hi + (size_t)(NL + l) * HD * HD, Wt_lo + (size_t)(NL + l) * HD * HD,
        b2 + (size_t)l * HD, Z2, st + 512,
        ptr_row, adjc, cmb + (size_t)(l + 1 < NL ? l + 1 : NL - 1) * 512 * HD,
        (l < NL - 1) ? Z1 : nullptr);
  }

  // ---- pooled head (BN of layer 4 from raw sums, no relu) ----
  pool_final_k<<<NG, 128, 0, stream>>>(Z2, stats + 4 * 1024 + 512,
      bn_g + 4 * HD, bn_b + 4 * HD, gp, cw1, cb1, cw2, cb2, out);
}

// Round 11
// 1328.013 us; speedup vs baseline: 1.0798x; 1.0798x over previous
//
#include <hip/hip_runtime.h>
#include <cstdint>

#define NN 300000
#define NE 600000
#define HD 128
#define NL 5
#define NG 8192
#define AVOC 128
#define BVOC 8
#define NAF 9
#define NBF 3
#define BN_EPS 1e-5f

#define SCAN_B 2048
#define SCAN_NB ((NN + SCAN_B - 1) / SCAN_B)   // 147

#define G1ROWS 128
#define G1BLK ((NN + G1ROWS - 1) / G1ROWS)     // 2344  (divisible by 8)
#define GBM 256
#define GBLK ((NN + GBM - 1) / GBM)            // 1172

typedef unsigned short u16;
typedef unsigned int u32;
typedef __attribute__((ext_vector_type(8))) short bf16x8;
typedef __attribute__((ext_vector_type(4))) float f32x4;

static __device__ __forceinline__ void atomAddF(float* p, float v) { unsafeAtomicAdd(p, v); }

static __device__ __forceinline__ float bf2f(u16 v) {
  union { u32 u; float f; } c; c.u = ((u32)v) << 16; return c.f;
}
static __device__ __forceinline__ u16 f2bf(float f) {
  union { float f; u32 u; } c; c.f = f;
  u32 u = c.u;
  return (u16)((u + 0x7FFFu + ((u >> 16) & 1u)) >> 16);  // RNE
}
static __device__ __forceinline__ u32 cvtpk(float a, float b) {
  u32 r;
  asm("v_cvt_pk_bf16_f32 %0, %1, %2" : "=v"(r) : "v"(a), "v"(b));
  return r;  // lo16 = bf16(a), hi16 = bf16(b), RNE
}
static __device__ __forceinline__ void unp8(uint4 p, float* v) {
  v[0] = bf2f((u16)(p.x & 0xffff)); v[1] = bf2f((u16)(p.x >> 16));
  v[2] = bf2f((u16)(p.y & 0xffff)); v[3] = bf2f((u16)(p.y >> 16));
  v[4] = bf2f((u16)(p.z & 0xffff)); v[5] = bf2f((u16)(p.z >> 16));
  v[6] = bf2f((u16)(p.w & 0xffff)); v[7] = bf2f((u16)(p.w >> 16));
}
static __device__ __forceinline__ uint4 pk8(const float* v) {
  uint4 p;
  p.x = ((u32)f2bf(v[1]) << 16) | f2bf(v[0]);
  p.y = ((u32)f2bf(v[3]) << 16) | f2bf(v[2]);
  p.z = ((u32)f2bf(v[5]) << 16) | f2bf(v[4]);
  p.w = ((u32)f2bf(v[7]) << 16) | f2bf(v[6]);
  return p;
}

// split fp32[8] -> hi bf16x8 + lo bf16x8  (hi+lo represents v to ~2^-17 rel)
static __device__ __forceinline__ void split8(const float* v, bf16x8& hi, bf16x8& lo) {
  union { u32 u[4]; bf16x8 h; } H, L;
  H.u[0] = cvtpk(v[0], v[1]); H.u[1] = cvtpk(v[2], v[3]);
  H.u[2] = cvtpk(v[4], v[5]); H.u[3] = cvtpk(v[6], v[7]);
  float r[8];
  r[0] = bf2f((u16)(H.u[0] & 0xffff)); r[1] = bf2f((u16)(H.u[0] >> 16));
  r[2] = bf2f((u16)(H.u[1] & 0xffff)); r[3] = bf2f((u16)(H.u[1] >> 16));
  r[4] = bf2f((u16)(H.u[2] & 0xffff)); r[5] = bf2f((u16)(H.u[2] >> 16));
  r[6] = bf2f((u16)(H.u[3] & 0xffff)); r[7] = bf2f((u16)(H.u[3] >> 16));
  L.u[0] = cvtpk(v[0] - r[0], v[1] - r[1]); L.u[1] = cvtpk(v[2] - r[2], v[3] - r[3]);
  L.u[2] = cvtpk(v[4] - r[4], v[5] - r[5]); L.u[3] = cvtpk(v[6] - r[6], v[7] - r[7]);
  hi = H.h; lo = L.h;
}

// ================= CSR construction =================
__global__ __launch_bounds__(256) void count_k(const int* __restrict__ ei,
    int* __restrict__ cnt_row, int* __restrict__ cnt_col) {
  int e = blockIdx.x * 256 + threadIdx.x;
  if (e >= NE) return;
  atomicAdd(&cnt_row[ei[e]], 1);
  atomicAdd(&cnt_col[ei[NE + e]], 1);
}

__global__ __launch_bounds__(256) void scan_block_k(int* __restrict__ P, int* __restrict__ bsum) {
  __shared__ int s[256];
  int b = blockIdx.x, t = threadIdx.x;
  int base = b * SCAN_B + t * 8;
  int v[8]; int ts = 0;
#pragma unroll
  for (int j = 0; j < 8; j++) { v[j] = (base + j < NN) ? P[base + j] : 0; ts += v[j]; }
  s[t] = ts;
  __syncthreads();
  for (int off = 1; off < 256; off <<= 1) {
    int tmp = 0;
    if (t >= off) tmp = s[t - off];
    __syncthreads();
    if (t >= off) s[t] += tmp;
    __syncthreads();
  }
  if (t == 255) bsum[b] = s[255];
  int run = (t == 0) ? 0 : s[t - 1];
#pragma unroll
  for (int j = 0; j < 8; j++) {
    if (base + j < NN) P[base + j] = run;
    run += v[j];
  }
}

__global__ __launch_bounds__(256) void scan_tops_k(int* __restrict__ bsum, int* __restrict__ totOut) {
  __shared__ int s[256];
  int t = threadIdx.x;
  s[t] = (t < SCAN_NB) ? bsum[t] : 0;
  __syncthreads();
  for (int off = 1; off < 256; off <<= 1) {
    int tmp = 0;
    if (t >= off) tmp = s[t - off];
    __syncthreads();
    if (t >= off) s[t] += tmp;
    __syncthreads();
  }
  if (t < SCAN_NB) bsum[t] = (t == 0) ? 0 : s[t - 1];
  if (t == 255) *totOut = s[255];
}

__global__ __launch_bounds__(256) void scan_add_k(int* __restrict__ P, const int* __restrict__ bsum) {
  int b = blockIdx.x, t = threadIdx.x;
  int off = bsum[b];
  int base = b * SCAN_B + t * 8;
#pragma unroll
  for (int j = 0; j < 8; j++)
    if (base + j < NN) P[base + j] += off;
}

// fill: adjc = combined bond-attr index (u16) in CSR-row order; adj_col = src node ids
__global__ __launch_bounds__(256) void fill_k(const int* __restrict__ ei,
    const int* __restrict__ ea,
    const int* __restrict__ ptr_row, const int* __restrict__ ptr_col,
    int* __restrict__ fillr, int* __restrict__ fillc,
    u16* __restrict__ adjc, int* __restrict__ adj_col) {
  int e = blockIdx.x * 256 + threadIdx.x;
  if (e >= NE) return;
  int r = ei[e], c = ei[NE + e];
  int a0 = ea[e * 3 + 0], a1 = ea[e * 3 + 1], a2 = ea[e * 3 + 2];
  int p1 = atomicAdd(&fillr[r], 1);
  adjc[ptr_row[r] + p1] = (u16)(a0 + (a1 << 3) + (a2 << 6));
  int p2 = atomicAdd(&fillc[c], 1);
  adj_col[ptr_col[c] + p2] = r;
}

__global__ __launch_bounds__(256) void inv_k(const int* __restrict__ ptr_row, float* __restrict__ inv) {
  int n = blockIdx.x * 256 + threadIdx.x;
  if (n < NN) inv[n] = 1.0f / ((float)(ptr_row[n + 1] - ptr_row[n]) + 1.0f);
}

__global__ __launch_bounds__(256) void gp_k(const int* __restrict__ batch, int* __restrict__ gp) {
  int g = blockIdx.x * 256 + threadIdx.x;
  if (g > NG) return;
  int lo = 0, hi = NN;
  while (lo < hi) { int mid = (lo + hi) >> 1; if (batch[mid] < g) lo = mid + 1; else hi = mid; }
  gp[g] = lo;
}

// W split/transpose: Wt[m][c][k] = bf16_hi/lo of W_m[k][c];  m<5 -> w1[m], else w2[m-5]
__global__ __launch_bounds__(256) void wsplit_k(const float* __restrict__ w1,
    const float* __restrict__ w2, u16* __restrict__ Wt_hi, u16* __restrict__ Wt_lo) {
  int m = blockIdx.x;
  const float* W = (m < NL) ? (w1 + (size_t)m * HD * HD) : (w2 + (size_t)(m - NL) * HD * HD);
  int t = threadIdx.x;
  for (int p = 0; p < 64; p++) {
    int o = p * 256 + t;            // linear over [c][k]
    int c = o >> 7, k = o & 127;
    float w = W[k * HD + c];
    u16 hi = f2bf(w);
    float lo = w - bf2f(hi);
    Wt_hi[(size_t)m * HD * HD + o] = hi;
    Wt_lo[(size_t)m * HD * HD + o] = f2bf(lo);
  }
}

// combined bond table in BF16: cmb[l][c][ch] = bf16(emb0[c&7] + emb1[(c>>3)&7] + emb2[c>>6])
__global__ __launch_bounds__(128) void cmb_k(const float* __restrict__ bond_emb,
    u16* __restrict__ cmb) {
  int b = blockIdx.x;                 // l*512 + c
  int l = b >> 9, c = b & 511;
  int t = threadIdx.x;
  const float* be = bond_emb + (size_t)l * NBF * BVOC * HD;
  float v = be[(c & 7) * HD + t] + be[(BVOC + ((c >> 3) & 7)) * HD + t]
          + be[(2 * BVOC + (c >> 6)) * HD + t];
  cmb[(size_t)b * HD + t] = f2bf(v);
}

// ================= model kernels =================

// bond + h_in via precomputed bf16 cmb table + CSR-ordered adjc (u16).
// Fused with either the atom encoder (ENC, layer 0) or prev layer's BN+relu
// (BN affine computed in-kernel from raw sums).  h_in -> A (bf16).
template<bool ENC>
__global__ __launch_bounds__(256) void bond_k(
    const u16* __restrict__ cmb, const int* __restrict__ ptr_row,
    const u16* __restrict__ adjc, const float* __restrict__ inv,
    const int* __restrict__ x, const float* __restrict__ emb,
    const u16* __restrict__ Z2, const float* __restrict__ stR,
    const float* __restrict__ bg, const float* __restrict__ bb_,
    u16* __restrict__ A) {
  __shared__ int sx[16 * NAF];
  __shared__ float sss[256];
  int t = threadIdx.x;
  int nb = blockIdx.x * 16;
  int n = nb + (t >> 4);
  int c8 = t & 15;
  if constexpr (ENC) {
    if (t < 16 * NAF && nb * NAF + t < NN * NAF) sx[t] = x[nb * NAF + t];
    __syncthreads();
  } else {
    if (t < 128) {
      float mean = stR[t] * (1.0f / NN);
      float var = stR[128 + t] * (1.0f / NN) - mean * mean;
      float sc = bg[t] * rsqrtf(var + BN_EPS);
      sss[t] = sc;
      sss[128 + t] = fmaf(-mean, sc, bb_[t]);
    }
    __syncthreads();
  }
  if (n >= NN) return;
  int beg = ptr_row[n], end = ptr_row[n + 1];
  float acc[8] = {0.f, 0.f, 0.f, 0.f, 0.f, 0.f, 0.f, 0.f};
  {
    int i = beg;
    int ca = (beg < end) ? (int)adjc[beg] : 0;
    int cb = (beg + 1 < end) ? (int)adjc[beg + 1] : 0;
    while (i + 1 < end) {
      uint4 pa = *(const uint4*)(cmb + ((size_t)ca << 7) + c8 * 8);
      uint4 pb = *(const uint4*)(cmb + ((size_t)cb << 7) + c8 * 8);
      i += 2;
      if (i < end)     ca = (int)adjc[i];
      if (i + 1 < end) cb = (int)adjc[i + 1];
      float va[8], vb[8];
      unp8(pa, va); unp8(pb, vb);
#pragma unroll
      for (int j = 0; j < 8; j++) acc[j] += va[j];
#pragma unroll
      for (int j = 0; j < 8; j++) acc[j] += vb[j];
    }
    if (i < end) {
      uint4 pa = *(const uint4*)(cmb + ((size_t)ca << 7) + c8 * 8);
      float va[8]; unp8(pa, va);
#pragma unroll
      for (int j = 0; j < 8; j++) acc[j] += va[j];
    }
  }
  float h[8];
  if constexpr (ENC) {
#pragma unroll
    for (int j = 0; j < 8; j++) h[j] = 0.f;
#pragma unroll
    for (int f = 0; f < NAF; f++) {
      int v = sx[(t >> 4) * NAF + f];
      const float* e = emb + ((size_t)(f * AVOC + v)) * HD + c8 * 8;
      float4 e0 = *(const float4*)e;
      float4 e1 = *(const float4*)(e + 4);
      h[0] += e0.x; h[1] += e0.y; h[2] += e0.z; h[3] += e0.w;
      h[4] += e1.x; h[5] += e1.y; h[6] += e1.z; h[7] += e1.w;
    }
  } else {
    uint4 p = *(const uint4*)(Z2 + (size_t)n * HD + c8 * 8);
    unp8(p, h);
#pragma unroll
    for (int j = 0; j < 8; j++)
      h[j] = fmaxf(fmaf(h[j], sss[c8 * 8 + j], sss[128 + c8 * 8 + j]), 0.f);
  }
  float iv = inv[n];
#pragma unroll
  for (int j = 0; j < 8; j++) h[j] = fmaf(acc[j], iv, h[j]);
  *(uint4*)(A + (size_t)n * HD + c8 * 8) = pk8(h);
}

// ---------------- GEMM1 with fused GIN aggregation (gather hoisted, unroll-2,
// XCD-aware block swizzle: 2344 % 8 == 0 -> simple bijective remap) ----------------
__global__ __launch_bounds__(512, 4) void gemm1_aggr_k(
    const u16* __restrict__ A, const int* __restrict__ ptr_col,
    const int* __restrict__ adj_col, const float* __restrict__ eps, int lyr,
    const u16* __restrict__ Whi, const u16* __restrict__ Wlo,
    const float* __restrict__ bias, u16* __restrict__ Z1,
    float* __restrict__ stats) {
  __shared__ u16 sW[2 * HD * HD];     // 64 KB: hi then lo, [col][k], XOR-swizzled
  const int tid = threadIdx.x;
#pragma unroll
  for (int p = 0; p < 4; p++) {
    int idx = tid + p * 512;
    int col = idx >> 4, k16 = idx & 15;
    uint4 vh = *(const uint4*)(Whi + idx * 8);
    uint4 vl = *(const uint4*)(Wlo + idx * 8);
    int so = (col << 7) + ((k16 << 3) ^ ((col & 7) << 3));
    *(uint4*)(sW + so) = vh;
    *(uint4*)(sW + HD * HD + so) = vl;
  }
  __syncthreads();

  // XCD swizzle: consecutive data-blocks land on the same XCD's L2
  const int bswz = (blockIdx.x & 7) * (G1BLK >> 3) + (blockIdx.x >> 3);

  const float se = 1.0f + eps[lyr];
  const int l = tid & 63, w = tid >> 6;
  const int lr = l & 15, lk = l >> 4;
  const int rw = bswz * G1ROWS + w * 16;        // wave's 16 rows
  const int gr = rw + lr;                       // this lane's row
  const int kb0 = lk * 8;                       // lane's col base within each 32-chunk

  float z[4][8];
#pragma unroll
  for (int ks = 0; ks < 4; ks++)
#pragma unroll
    for (int j = 0; j < 8; j++) z[ks][j] = 0.f;

  if (gr < NN) {
    const u16* ap = A + (size_t)gr * HD + kb0;
    uint4 s0 = *(const uint4*)(ap);
    uint4 s1 = *(const uint4*)(ap + 32);
    uint4 s2 = *(const uint4*)(ap + 64);
    uint4 s3 = *(const uint4*)(ap + 96);
    int beg = ptr_col[gr], end = ptr_col[gr + 1];
    {
      float v[8];
      unp8(s0, v);
#pragma unroll
      for (int j = 0; j < 8; j++) z[0][j] = v[j] * se;
      unp8(s1, v);
#pragma unroll
      for (int j = 0; j < 8; j++) z[1][j] = v[j] * se;
      unp8(s2, v);
#pragma unroll
      for (int j = 0; j < 8; j++) z[2][j] = v[j] * se;
      unp8(s3, v);
#pragma unroll
      for (int j = 0; j < 8; j++) z[3][j] = v[j] * se;
    }
    int i = beg;
    int srcA = (beg < end) ? adj_col[beg] : 0;
    int srcB = (beg + 1 < end) ? adj_col[beg + 1] : 0;
    while (i + 1 < end) {
      const u16* pa = A + (size_t)srcA * HD + kb0;
      const u16* pb = A + (size_t)srcB * HD + kb0;
      uint4 a0 = *(const uint4*)(pa);
      uint4 a1 = *(const uint4*)(pa + 32);
      uint4 a2 = *(const uint4*)(pa + 64);
      uint4 a3 = *(const uint4*)(pa + 96);
      uint4 b0 = *(const uint4*)(pb);
      uint4 b1 = *(const uint4*)(pb + 32);
      uint4 b2 = *(const uint4*)(pb + 64);
      uint4 b3 = *(const uint4*)(pb + 96);
      i += 2;
      if (i < end)     srcA = adj_col[i];
      if (i + 1 < end) srcB = adj_col[i + 1];
      float u[8];
      unp8(a0, u);
#pragma unroll
      for (int j = 0; j < 8; j++) z[0][j] += u[j];
      unp8(a1, u);
#pragma unroll
      for (int j = 0; j < 8; j++) z[1][j] += u[j];
      unp8(a2, u);
#pragma unroll
      for (int j = 0; j < 8; j++) z[2][j] += u[j];
      unp8(a3, u);
#pragma unroll
      for (int j = 0; j < 8; j++) z[3][j] += u[j];
      unp8(b0, u);
#pragma unroll
      for (int j = 0; j < 8; j++) z[0][j] += u[j];
      unp8(b1, u);
#pragma unroll
      for (int j = 0; j < 8; j++) z[1][j] += u[j];
      unp8(b2, u);
#pragma unroll
      for (int j = 0; j < 8; j++) z[2][j] += u[j];
      unp8(b3, u);
#pragma unroll
      for (int j = 0; j < 8; j++) z[3][j] += u[j];
    }
    if (i < end) {
      const u16* pa = A + (size_t)srcA * HD + kb0;
      uint4 a0 = *(const uint4*)(pa);
      uint4 a1 = *(const uint4*)(pa + 32);
      uint4 a2 = *(const uint4*)(pa + 64);
      uint4 a3 = *(const uint4*)(pa + 96);
      float u[8];
      unp8(a0, u);
#pragma unroll
      for (int j = 0; j < 8; j++) z[0][j] += u[j];
      unp8(a1, u);
#pragma unroll
      for (int j = 0; j < 8; j++) z[1][j] += u[j];
      unp8(a2, u);
#pragma unroll
      for (int j = 0; j < 8; j++) z[2][j] += u[j];
      unp8(a3, u);
#pragma unroll
      for (int j = 0; j < 8; j++) z[3][j] += u[j];
    }
  }

  bf16x8 ah[4], al[4];
#pragma unroll
  for (int ks = 0; ks < 4; ks++) split8(z[ks], ah[ks], al[ks]);

  f32x4 acc[8];
#pragma unroll
  for (int jt = 0; jt < 8; jt++) acc[jt] = (f32x4){0.f, 0.f, 0.f, 0.f};
#pragma unroll
  for (int ks = 0; ks < 4; ks++) {
    const int kb = ks * 32 + kb0;
#pragma unroll
    for (int jt = 0; jt < 8; jt++) {
      int col = jt * 16 + lr;
      int so = (col << 7) + (kb ^ ((col & 7) << 3));
      bf16x8 bh = *(const bf16x8*)(sW + so);
      bf16x8 bl = *(const bf16x8*)(sW + HD * HD + so);
      acc[jt] = __builtin_amdgcn_mfma_f32_16x16x32_bf16(ah[ks], bh, acc[jt], 0, 0, 0);
      acc[jt] = __builtin_amdgcn_mfma_f32_16x16x32_bf16(al[ks], bh, acc[jt], 0, 0, 0);
      acc[jt] = __builtin_amdgcn_mfma_f32_16x16x32_bf16(ah[ks], bl, acc[jt], 0, 0, 0);
    }
  }

  // epilogue: +bias, BN stats (fp32 pre-rounding), packed bf16 stores
  float bb[8];
#pragma unroll
  for (int jt = 0; jt < 8; jt++) bb[jt] = bias[jt * 16 + lr];
  float cs[8], cq[8];
#pragma unroll
  for (int jt = 0; jt < 8; jt++) { cs[jt] = 0.f; cq[jt] = 0.f; }
#pragma unroll
  for (int j = 0; j < 4; j++) {
    int gr2 = rw + lk * 4 + j;
    bool ok = gr2 < NN;
#pragma unroll
    for (int jt = 0; jt < 8; jt++) {
      float o = acc[jt][j] + bb[jt];
      if (ok) { cs[jt] += o; cq[jt] += o * o; }
      float on = __shfl_xor(o, 1);
      u32 pw = cvtpk(o, on);
      if (ok && !(l & 1))
        *(u32*)(Z1 + (size_t)gr2 * HD + jt * 16 + lr) = pw;
    }
  }
#pragma unroll
  for (int jt = 0; jt < 8; jt++) {
    cs[jt] += __shfl_xor(cs[jt], 16); cs[jt] += __shfl_xor(cs[jt], 32);
    cq[jt] += __shfl_xor(cq[jt], 16); cq[jt] += __shfl_xor(cq[jt], 32);
  }
  __syncthreads();
  float* sS = (float*)sW;
  if (lk == 0) {
#pragma unroll
    for (int jt = 0; jt < 8; jt++) {
      sS[w * HD + jt * 16 + lr] = cs[jt];
      sS[1024 + w * HD + jt * 16 + lr] = cq[jt];
    }
  }
  __syncthreads();
  if (tid < HD) {
    float s = 0.f, q = 0.f;
#pragma unroll
    for (int g = 0; g < 8; g++) { s += sS[g * HD + tid]; q += sS[1024 + g * HD + tid]; }
    atomAddF(&stats[tid], s);
    atomAddF(&stats[HD + tid], q);
  }
}

// ---------------- GEMM2: relu(BN1(Z1)) @ W2 + b2 -> Z2 bf16 + BN stats ----------------
// BN1 affine computed in-kernel from gemm1's raw sums.
__global__ __launch_bounds__(512, 4) void gemm2_k(
    const u16* __restrict__ Z1, const float* __restrict__ stR,
    const float* __restrict__ g1, const float* __restrict__ b1_,
    const u16* __restrict__ Whi, const u16* __restrict__ Wlo,
    const float* __restrict__ bias, u16* __restrict__ Z2,
    float* __restrict__ stats) {
  __shared__ u16 sW[2 * HD * HD];
  __shared__ float sss[256];
  const int tid = threadIdx.x;
#pragma unroll
  for (int p = 0; p < 4; p++) {
    int idx = tid + p * 512;
    int col = idx >> 4, k16 = idx & 15;
    uint4 vh = *(const uint4*)(Whi + idx * 8);
    uint4 vl = *(const uint4*)(Wlo + idx * 8);
    int so = (col << 7) + ((k16 << 3) ^ ((col & 7) << 3));
    *(uint4*)(sW + so) = vh;
    *(uint4*)(sW + HD * HD + so) = vl;
  }
  if (tid < 128) {
    float mean = stR[tid] * (1.0f / NN);
    float var = stR[128 + tid] * (1.0f / NN) - mean * mean;
    float sc = g1[tid] * rsqrtf(var + BN_EPS);
    sss[tid] = sc;
    sss[128 + tid] = fmaf(-mean, sc, b1_[tid]);
  }
  __syncthreads();

  const int l = tid & 63, w = tid >> 6;
  const int lr = l & 15, lk = l >> 4;
  const int rw = blockIdx.x * GBM + w * 32;
  f32x4 acc[2][8];
#pragma unroll
  for (int i = 0; i < 2; i++)
#pragma unroll
    for (int j = 0; j < 8; j++) acc[i][j] = (f32x4){0.f, 0.f, 0.f, 0.f};

#pragma unroll
  for (int ks = 0; ks < 4; ks++) {
    const int kb = ks * 32 + lk * 8;
    bf16x8 ah[2], al[2];
#pragma unroll
    for (int i = 0; i < 2; i++) {
      int gr = rw + i * 16 + lr;
      uint4 p = make_uint4(0u, 0u, 0u, 0u);
      if (gr < NN) p = *(const uint4*)(Z1 + (size_t)gr * HD + kb);
      float v[8]; unp8(p, v);
#pragma unroll
      for (int j = 0; j < 8; j++)
        v[j] = fmaxf(fmaf(v[j], sss[kb + j], sss[128 + kb + j]), 0.f);
      split8(v, ah[i], al[i]);
    }
#pragma unroll
    for (int jt = 0; jt < 8; jt++) {
      int col = jt * 16 + lr;
      int so = (col << 7) + (kb ^ ((col & 7) << 3));
      bf16x8 bh = *(const bf16x8*)(sW + so);
      bf16x8 bl = *(const bf16x8*)(sW + HD * HD + so);
#pragma unroll
      for (int i = 0; i < 2; i++) {
        acc[i][jt] = __builtin_amdgcn_mfma_f32_16x16x32_bf16(ah[i], bh, acc[i][jt], 0, 0, 0);
        acc[i][jt] = __builtin_amdgcn_mfma_f32_16x16x32_bf16(al[i], bh, acc[i][jt], 0, 0, 0);
        acc[i][jt] = __builtin_amdgcn_mfma_f32_16x16x32_bf16(ah[i], bl, acc[i][jt], 0, 0, 0);
      }
    }
  }

  float bb[8];
#pragma unroll
  for (int jt = 0; jt < 8; jt++) bb[jt] = bias[jt * 16 + lr];
  float cs[8], cq[8];
#pragma unroll
  for (int jt = 0; jt < 8; jt++) { cs[jt] = 0.f; cq[jt] = 0.f; }
#pragma unroll
  for (int i = 0; i < 2; i++)
#pragma unroll
    for (int j = 0; j < 4; j++) {
      int gr = rw + i * 16 + lk * 4 + j;
      bool ok = gr < NN;
#pragma unroll
      for (int jt = 0; jt < 8; jt++) {
        float o = acc[i][jt][j] + bb[jt];
        if (ok) { cs[jt] += o; cq[jt] += o * o; }
        float on = __shfl_xor(o, 1);
        u32 pw = cvtpk(o, on);
        if (ok && !(l & 1))
          *(u32*)(Z2 + (size_t)gr * HD + jt * 16 + lr) = pw;
      }
    }
#pragma unroll
  for (int jt = 0; jt < 8; jt++) {
    cs[jt] += __shfl_xor(cs[jt], 16); cs[jt] += __shfl_xor(cs[jt], 32);
    cq[jt] += __shfl_xor(cq[jt], 16); cq[jt] += __shfl_xor(cq[jt], 32);
  }
  __syncthreads();
  float* sS = (float*)sW;
  if (lk == 0) {
#pragma unroll
    for (int jt = 0; jt < 8; jt++) {
      sS[w * HD + jt * 16 + lr] = cs[jt];
      sS[1024 + w * HD + jt * 16 + lr] = cq[jt];
    }
  }
  __syncthreads();
  if (tid < HD) {
    float s = 0.f, q = 0.f;
#pragma unroll
    for (int g = 0; g < 8; g++) { s += sS[g * HD + tid]; q += sS[1024 + g * HD + tid]; }
    atomAddF(&stats[tid], s);
    atomAddF(&stats[HD + tid], q);
  }
}

// fused BN (layer 4, computed from raw sums, no relu) + global_add_pool + MLP head
__global__ __launch_bounds__(128) void pool_final_k(const u16* __restrict__ Z2,
    const float* __restrict__ stR,
    const float* __restrict__ bg, const float* __restrict__ bb_,
    const int* __restrict__ gp,
    const float* __restrict__ cw1, const float* __restrict__ cb1,
    const float* __restrict__ cw2, const float* __restrict__ cb2,
    float* __restrict__ out) {
  __shared__ float sp[128];
  __shared__ float sh[128];
  int g = blockIdx.x, t = threadIdx.x;
  float mean = stR[t] * (1.0f / NN);
  float var = stR[128 + t] * (1.0f / NN) - mean * mean;
  float sc = bg[t] * rsqrtf(var + BN_EPS);
  float shf = fmaf(-mean, sc, bb_[t]);
  int beg = gp[g], end = gp[g + 1];
  float acc = 0.f;
  for (int n = beg; n < end; n++) acc += bf2f(Z2[(size_t)n * HD + t]);
  sp[t] = fmaf(acc, sc, (float)(end - beg) * shf);
  __syncthreads();
  float h1 = cb1[t];
#pragma unroll
  for (int k = 0; k < HD; k++) h1 = fmaf(sp[k], cw1[k * HD + t], h1);
  h1 = fmaxf(h1, 0.f);
  sh[t] = h1 * cw2[t];
  __syncthreads();
  for (int s = 64; s >= 1; s >>= 1) {
    if (t < s) sh[t] += sh[t + s];
    __syncthreads();
  }
  if (t == 0) out[g] = sh[0] + cb2[0];
}

extern "C" void kernel_launch(void* const* d_in, const int* in_sizes, int n_in,
                              void* d_out, int out_size, void* d_ws, size_t ws_size,
                              hipStream_t stream) {
  const int*   x        = (const int*)d_in[0];
  const int*   ei       = (const int*)d_in[1];
  const int*   ea       = (const int*)d_in[2];
  const int*   batch    = (const int*)d_in[3];
  const float* atom_emb = (const float*)d_in[4];
  const float* bond_emb = (const float*)d_in[5];
  const float* eps      = (const float*)d_in[6];
  const float* w1       = (const float*)d_in[7];
  const float* b1       = (const float*)d_in[8];
  const float* bn1_g    = (const float*)d_in[9];
  const float* bn1_b    = (const float*)d_in[10];
  const float* w2       = (const float*)d_in[11];
  const float* b2       = (const float*)d_in[12];
  const float* bn_g     = (const float*)d_in[13];
  const float* bn_b     = (const float*)d_in[14];
  const float* cw1      = (const float*)d_in[15];
  const float* cb1      = (const float*)d_in[16];
  const float* cw2      = (const float*)d_in[17];
  const float* cb2      = (const float*)d_in[18];
  float* out = (float*)d_out;

  const size_t NH = (size_t)NN * HD;
  float* ws = (float*)d_ws;
  float* stats   = ws;                               // 5*1024 floats (raw sums)
  int*   ptr_row = (int*)(ws + 5 * 1024);            // NN+1
  int*   ptr_col = ptr_row + (NN + 1);               // NN+1
  u16*   adjc    = (u16*)(ptr_col + (NN + 1));       // NE u16 (slot sized NE ints)
  int*   adj_col = (int*)adjc + NE;                  // NE
  int*   gp      = adj_col + NE;                     // NG+1
  float* inv     = (float*)(gp + (NG + 1));          // NN
  size_t off = 5 * 1024 + 2 * (size_t)(NN + 1) + 2 * (size_t)NE + (NG + 1) + NN;
  off = (off + 3) & ~(size_t)3;                      // 16B align
  float* B = ws + off;                               // NH fp32 bytes: Z1 | Z2 (bf16 halves)
  u16*   Z1 = (u16*)B;                               // lower NH*2 bytes
  u16*   Z2 = Z1 + NH;                               // upper NH*2 bytes
  u16*   A  = (u16*)(B + NH);                        // NH bf16 (h_in)
  u16*   Wt_hi = A + NH;                             // 10 * 128*128 bf16
  u16*   Wt_lo = Wt_hi + 10 * HD * HD;               // 10 * 128*128 bf16
  u16*   cmb   = Wt_lo + 10 * HD * HD;               // 5 * 512 * 128 bf16
  // setup-only temps aliased into B (first written by gemm1_aggr in layer 0)
  int* fillr = (int*)B;
  int* fillc = fillr + NN;
  int* bsums = fillc + NN;                           // SCAN_NB ints

  const int nb_node = (NN + 15) / 16;                        // 18750
  const int nb_n256 = (NN + 255) / 256;                      // 1172
  const int nb_e    = (NE + 255) / 256;                      // 2344

  // ---- setup: CSR build + weight split + bond table + graph offsets ----
  hipMemsetAsync(stats, 0, 5 * 1024 * sizeof(float), stream);
  hipMemsetAsync(ptr_row, 0, 2 * (NN + 1) * sizeof(int), stream);
  hipMemsetAsync(fillr, 0, 2 * NN * sizeof(int), stream);

  count_k<<<nb_e, 256, 0, stream>>>(ei, ptr_row, ptr_col);
  scan_block_k<<<SCAN_NB, 256, 0, stream>>>(ptr_row, bsums);
  scan_tops_k<<<1, 256, 0, stream>>>(bsums, &ptr_row[NN]);
  scan_add_k<<<SCAN_NB, 256, 0, stream>>>(ptr_row, bsums);
  scan_block_k<<<SCAN_NB, 256, 0, stream>>>(ptr_col, bsums);
  scan_tops_k<<<1, 256, 0, stream>>>(bsums, &ptr_col[NN]);
  scan_add_k<<<SCAN_NB, 256, 0, stream>>>(ptr_col, bsums);
  inv_k<<<nb_n256, 256, 0, stream>>>(ptr_row, inv);
  fill_k<<<nb_e, 256, 0, stream>>>(ei, ea, ptr_row, ptr_col, fillr, fillc, adjc, adj_col);
  wsplit_k<<<2 * NL, 256, 0, stream>>>(w1, w2, Wt_hi, Wt_lo);
  cmb_k<<<NL * 512, 128, 0, stream>>>(bond_emb, cmb);
  gp_k<<<(NG + 1 + 255) / 256, 256, 0, stream>>>(batch, gp);

  // ---- layers ----
  for (int l = 0; l < NL; l++) {
    const u16* cl = cmb + (size_t)l * 512 * HD;
    float* st = stats + (size_t)l * 1024;
    if (l == 0) {
      bond_k<true><<<nb_node, 256, 0, stream>>>(cl, ptr_row, adjc, inv,
          x, atom_emb, nullptr, nullptr, nullptr, nullptr, A);
    } else {
      bond_k<false><<<nb_node, 256, 0, stream>>>(cl, ptr_row, adjc, inv,
          nullptr, nullptr, Z2, stats + (size_t)(l - 1) * 1024 + 512,
          bn_g + (size_t)(l - 1) * HD, bn_b + (size_t)(l - 1) * HD, A);
    }
    gemm1_aggr_k<<<G1BLK, 512, 0, stream>>>(A, ptr_col, adj_col, eps, l,
        Wt_hi + (size_t)l * HD * HD, Wt_lo + (size_t)l * HD * HD,
        b1 + (size_t)l * HD, Z1, st);
    gemm2_k<<<GBLK, 512, 0, stream>>>(Z1, st,
        bn1_g + (size_t)l * HD, bn1_b + (size_t)l * HD,
        Wt_hi + (size_t)(NL + l) * HD * HD, Wt_lo + (size_t)(NL + l) * HD * HD,
        b2 + (size_t)l * HD, Z2, st + 512);
  }

  // ---- pooled head (BN of layer 4 from raw sums, no relu) ----
  pool_final_k<<<NG, 128, 0, stream>>>(Z2, stats + 4 * 1024 + 512,
      bn_g + 4 * HD, bn_b + 4 * HD, gp, cw1, cb1, cw2, cb2, out);
}